// Round 6
// baseline (73.275 us; speedup 1.0000x reference)
//
#include <hip/hip_runtime.h>
#include <hip/hip_bf16.h>

typedef __attribute__((ext_vector_type(8))) short bf16x8;
typedef __attribute__((ext_vector_type(4))) float f32x4;
typedef unsigned short u16;
typedef unsigned int u32;

#define NH 8
#define NN 4096
#define MM 4096

__device__ __forceinline__ u16 f2bf(float f) {
  u32 b = __float_as_uint(f);
  b += 0x7FFFu + ((b >> 16) & 1u);   // RNE to bf16
  return (u16)(b >> 16);
}

// pack two positive floats to bf16 pair {lo:a, hi:b}, round-half-up
__device__ __forceinline__ u32 pack_rnu(float a, float b) {
  u32 ua = __float_as_uint(a) + 0x8000u;
  u32 ub = __float_as_uint(b) + 0x8000u;
#if __has_builtin(__builtin_amdgcn_perm)
  return __builtin_amdgcn_perm(ub, ua, 0x07060302u);  // {ua.b2,ua.b3,ub.b2,ub.b3}
#else
  return (ua >> 16) | (ub & 0xFFFF0000u);
#endif
}

#if __has_builtin(__builtin_amdgcn_exp2f)
__device__ __forceinline__ float exp2_fast(float x) { return __builtin_amdgcn_exp2f(x); }
#else
__device__ __forceinline__ float exp2_fast(float x) { return __expf(x * 0.69314718055994531f); }
#endif

// ---------------- fused projections: blocks 0..255 = q/k, 256..383 = v ----------------
// v is written transposed AND key-permuted within each 32-key chunk:
//   position p (0..31) holds key k(p) = 16*((p>>2)&1) + 4*(p>>3) + (p&3)
// so flash's PV A-fragment (slot map k = 4g+(j&3)+16(j>>2)) is one b128 at 8g.
__global__ __launch_bounds__(256) void proj_kernel(
    const float* __restrict__ x, const float* __restrict__ y,
    const float* __restrict__ Wq, const float* __restrict__ bq,
    const float* __restrict__ Wk, const float* __restrict__ bk,
    const float* __restrict__ Wv, const float* __restrict__ bv,
    u16* __restrict__ qs, u16* __restrict__ ks, u16* __restrict__ vT)
{
  __shared__ u16 sv[256][33];
  const int bid = blockIdx.x;
  const int tid = threadIdx.x;
  if (bid < 256) {
    // ---- q/k path ----
    int idx = bid * 256 + tid;                  // 65536 total
    int t = idx >> 15;                          // 0 = q (from x), 1 = k (from y)
    int h = (idx >> 12) & 7;
    int row = idx & 4095;
    const float* src = (t ? y : x) + row * 16;
    const float* W = (t ? Wk : Wq) + (h << 9);
    const float* b = (t ? bk : bq) + (h << 5);
    // q scale = (1/sqrt(32)) * log2(e) so softmax is exp2(score)
    const float scale = t ? 1.0f : 0.25503635116465163f;
    float4 r4[4];
#pragma unroll
    for (int i = 0; i < 4; ++i) r4[i] = ((const float4*)src)[i];
    const float* r = (const float*)r4;
    u16* out = (t ? ks : qs) + (idx & 32767) * 32;      // (h*4096+row)*32
#pragma unroll
    for (int j = 0; j < 32; ++j) {
      float a = b[j];
#pragma unroll
      for (int i = 0; i < 16; ++i) a = fmaf(r[i], W[i * 32 + j], a);
      out[j] = f2bf(a * scale);
    }
  } else {
    // ---- v path ----
    int vb = bid - 256;
    int h = vb >> 4;
    int kb = (vb & 15) << 8;           // 256 keys per block
    const float* src = y + (kb + tid) * 16;
    const float* W = Wv + (h << 9);
    const float* b = bv + (h << 5);
    float4 r4[4];
#pragma unroll
    for (int i = 0; i < 4; ++i) r4[i] = ((const float4*)src)[i];
    const float* r = (const float*)r4;
#pragma unroll
    for (int j = 0; j < 32; ++j) {
      float a = b[j];
#pragma unroll
      for (int i = 0; i < 16; ++i) a = fmaf(r[i], W[i * 32 + j], a);
      sv[tid][j] = f2bf(a);
    }
    __syncthreads();
    int dv = tid >> 3;
    int c = (tid & 7) << 5;            // 32-key chunk
    u16* dst = vT + (((h << 5) + dv) << 12) + kb + c;
#pragma unroll
    for (int q = 0; q < 4; ++q) {      // positions 8q..8q+7 <- keys {4q+r, 16+4q+r}
      uint4 w;
      w.x = (u32)sv[c + 4 * q + 0][dv]      | ((u32)sv[c + 4 * q + 1][dv] << 16);
      w.y = (u32)sv[c + 4 * q + 2][dv]      | ((u32)sv[c + 4 * q + 3][dv] << 16);
      w.z = (u32)sv[c + 16 + 4 * q + 0][dv] | ((u32)sv[c + 16 + 4 * q + 1][dv] << 16);
      w.w = (u32)sv[c + 16 + 4 * q + 2][dv] | ((u32)sv[c + 16 + 4 * q + 3][dv] << 16);
      *(uint4*)(dst + q * 8) = w;
    }
  }
}

// ---------------- flash attention (key-split partials): S^T = K Q^T, O^T = V^T P^T ----
// Round-4/5 verified structure: KVBLK=128 single-buffer (2 barriers/stage),
// aligned strides, register prefetch (T14), no-max exp2 softmax, pack_rnu.
// V-fragment reads are now 4x ds_read_b128 (permuted vT layout).
#define KST 40                  // K LDS row stride in u16 (80 B, 16B-aligned)
#define VST 72                  // V LDS row stride in u16 (144 B, 16B-aligned)
#define VSZ (32 * VST)          // one 64-key V sub-tile

__global__ __launch_bounds__(256) void flash_kernel(
    const u16* __restrict__ qs, const u16* __restrict__ ksrc,
    const u16* __restrict__ vT, float* __restrict__ accP,
    float* __restrict__ lsumP)
{
  __shared__ u16 sK[128 * KST];    // 128 keys x 32 dq  (10240 B)
  __shared__ u16 sVT[2 * VSZ];     // 2 sub x 32 dv x 64 keys (9216 B)
  const int h = blockIdx.y;
  const int qt = blockIdx.x;
  const int z = blockIdx.z;
  const int nIter = (MM / 128) / gridDim.z;        // stages of 128 keys
  const int kb0 = z * (MM / gridDim.z);            // first key of this split
  const int tid = threadIdx.x;
  const int wv = tid >> 6;
  const int lane = tid & 63;
  const int d = lane & 15;        // qrow-in-16 / A-row index / C col
  const int g = lane >> 4;        // lane group
  const int qrow = (qt << 6) + (wv << 4) + d;

  union U4 { uint4 q; bf16x8 v; };
  // Q fragment, contiguous k-relabel: slot (g,j) -> k = 8g+j (same map on K side)
  U4 qf;
  qf.q = *(const uint4*)(qs + (((h << 12) + qrow) << 5) + (g << 3));

  float lsum = 0.f;
  f32x4 acc0 = {0.f, 0.f, 0.f, 0.f};
  f32x4 acc1 = {0.f, 0.f, 0.f, 0.f};
  const f32x4 zero = {0.f, 0.f, 0.f, 0.f};

  // staging addresses
  const u16* gK = ksrc + (h << 17) + (kb0 << 5) + ((tid >> 1) << 5) + ((tid & 1) << 4);
  const u16* gV = vT + (((h << 5) + (tid >> 3)) << 12) + kb0 + ((tid & 7) << 4);
  u16* wK = sK + (tid >> 1) * KST + ((tid & 1) << 4);
  u16* wV = sVT + ((tid & 7) >> 2) * VSZ + (tid >> 3) * VST + ((tid & 7) & 3) * 16;

  // prologue: stage this split's first 128 keys
  {
    uint4 a = *(const uint4*)gK, b = *(const uint4*)(gK + 8);
    uint4 c = *(const uint4*)gV, e = *(const uint4*)(gV + 8);
    *(uint4*)wK = a; *(uint4*)(wK + 8) = b;
    *(uint4*)wV = c; *(uint4*)(wV + 8) = e;
  }
  __syncthreads();

  auto compute = [&](const u16* kb, const u16* vb) {
    U4 af;
    f32x4 s[4];
#pragma unroll
    for (int t = 0; t < 4; ++t) {   // S^T subtile t: keys 16t+d, k = 8g+j contiguous
      af.q = *(const uint4*)(kb + (t * 16 + d) * KST + (g << 3));
      s[t] = __builtin_amdgcn_mfma_f32_16x16x32_bf16(af.v, qf.v, zero, 0, 0, 0);
    }
    float e[16];
#pragma unroll
    for (int t = 0; t < 4; ++t) {
      e[4 * t + 0] = exp2_fast(s[t].x);
      e[4 * t + 1] = exp2_fast(s[t].y);
      e[4 * t + 2] = exp2_fast(s[t].z);
      e[4 * t + 3] = exp2_fast(s[t].w);
    }
    float t0 = (e[0] + e[1]) + (e[2] + e[3]);
    float t1 = (e[4] + e[5]) + (e[6] + e[7]);
    float t2 = (e[8] + e[9]) + (e[10] + e[11]);
    float t3 = (e[12] + e[13]) + (e[14] + e[15]);
    lsum += (t0 + t1) + (t2 + t3);
    union { u32 w[4]; bf16x8 v; } pb0, pb1;
    pb0.w[0] = pack_rnu(e[0], e[1]);   pb0.w[1] = pack_rnu(e[2], e[3]);
    pb0.w[2] = pack_rnu(e[4], e[5]);   pb0.w[3] = pack_rnu(e[6], e[7]);
    pb1.w[0] = pack_rnu(e[8], e[9]);   pb1.w[1] = pack_rnu(e[10], e[11]);
    pb1.w[2] = pack_rnu(e[12], e[13]); pb1.w[3] = pack_rnu(e[14], e[15]);
    // O^T += V^T * P^T  (vT key-permuted: slot block for group g at position 8g)
    U4 vf;
    const u16* vp = vb + d * VST;
    vf.q = *(const uint4*)(vp + (g << 3));
    acc0 = __builtin_amdgcn_mfma_f32_16x16x32_bf16(vf.v, pb0.v, acc0, 0, 0, 0);
    vf.q = *(const uint4*)(vp + 32 + (g << 3));
    acc0 = __builtin_amdgcn_mfma_f32_16x16x32_bf16(vf.v, pb1.v, acc0, 0, 0, 0);
    vp += 16 * VST;
    vf.q = *(const uint4*)(vp + (g << 3));
    acc1 = __builtin_amdgcn_mfma_f32_16x16x32_bf16(vf.v, pb0.v, acc1, 0, 0, 0);
    vf.q = *(const uint4*)(vp + 32 + (g << 3));
    acc1 = __builtin_amdgcn_mfma_f32_16x16x32_bf16(vf.v, pb1.v, acc1, 0, 0, 0);
  };

#pragma unroll 1
  for (int it = 0; it < nIter; ++it) {
    uint4 a, b, c, e;
    if (it < nIter - 1) {            // prefetch next 128 keys into registers
      gK += 4096; gV += 128;
      a = *(const uint4*)gK; b = *(const uint4*)(gK + 8);
      c = *(const uint4*)gV; e = *(const uint4*)(gV + 8);
    }
    compute(sK, sVT);
    compute(sK + 64 * KST, sVT + VSZ);
    __syncthreads();               // all reads of current stage done
    if (it < nIter - 1) {
      *(uint4*)wK = a; *(uint4*)(wK + 8) = b;   // vmcnt drained under compute
      *(uint4*)wV = c; *(uint4*)(wV + 8) = e;
      __syncthreads();             // stage visible
    }
  }

  // cross-lane reduce of this split's denominator; store per qrow (g==0 lanes)
  lsum += __shfl_xor(lsum, 16);
  lsum += __shfl_xor(lsum, 32);
  if (g == 0)
    lsumP[((z * NH + h) << 12) + qrow] = lsum;
  // unnormalized partial O
  float* cp = accP + z * (NN * 256) + (qrow << 8) + (h << 5) + (g << 2);
  *(float4*)cp        = make_float4(acc0.x, acc0.y, acc0.z, acc0.w);
  *(float4*)(cp + 16) = make_float4(acc1.x, acc1.y, acc1.z, acc1.w);
}

// ---------------- fused combine + output projection ----------------
// out[n][c] = bo[c] + sum_j ( (sum_s accP[s][n][j]) / (sum_s lsum[s][h(j)][n]) ) * Wo[j][c]
__global__ __launch_bounds__(256) void out_gemm_kernel(
    const float* __restrict__ accP, const float* __restrict__ lsumP,
    const float* __restrict__ Wo, const float* __restrict__ bo,
    float* __restrict__ out, int S)
{
  __shared__ float sWo[4096];      // 16 KB
  __shared__ float sC[16][260];    // 16 rows, +4 pad (bank-conflict-free GEMM reads)
  __shared__ float sD[16][8];      // 1/denominator per (row, head)
  const int tid = threadIdx.x;
  const int n0 = blockIdx.x << 4;  // 16 rows per block

  // reciprocal denominators
  if (tid < 128) {
    int row = tid >> 3, hh = tid & 7;
    float l = 0.f;
    for (int s = 0; s < S; ++s) l += lsumP[((s * NH + hh) << 12) + n0 + row];
    sD[row][hh] = 1.0f / l;
  }
  for (int i = tid; i < 4096; i += 256) sWo[i] = Wo[i];
  __syncthreads();

  // sum splits + normalize into sC
#pragma unroll
  for (int e = 0; e < 16; ++e) {
    float o = 0.f;
    int gidx = ((n0 + e) << 8) + tid;
    for (int s = 0; s < S; ++s) o += accP[s * (NN * 256) + gidx];
    sC[e][tid] = o * sD[e][tid >> 5];
  }
  __syncthreads();

  // GEMM: 16 rows x 16 cols per block
  const int r = tid >> 4;
  const int c = tid & 15;
  const float* crow = &sC[r][0];
  float a = bo[c];
#pragma unroll 4
  for (int i4 = 0; i4 < 64; ++i4) {
    float4 cv = *(const float4*)(crow + i4 * 4);
    a = fmaf(cv.x, sWo[(i4 * 4 + 0) * 16 + c], a);
    a = fmaf(cv.y, sWo[(i4 * 4 + 1) * 16 + c], a);
    a = fmaf(cv.z, sWo[(i4 * 4 + 2) * 16 + c], a);
    a = fmaf(cv.w, sWo[(i4 * 4 + 3) * 16 + c], a);
  }
  out[(n0 << 4) + tid] = a;
}

extern "C" void kernel_launch(void* const* d_in, const int* in_sizes, int n_in,
                              void* d_out, int out_size, void* d_ws, size_t ws_size,
                              hipStream_t stream) {
  const float* x  = (const float*)d_in[0];
  const float* y  = (const float*)d_in[1];
  const float* Wq = (const float*)d_in[2];
  const float* bq = (const float*)d_in[3];
  const float* Wk = (const float*)d_in[4];
  const float* bk = (const float*)d_in[5];
  const float* Wv = (const float*)d_in[6];
  const float* bv = (const float*)d_in[7];
  const float* Wo = (const float*)d_in[8];
  const float* bo = (const float*)d_in[9];
  float* out = (float*)d_out;

  u16* qs = (u16*)d_ws;                       // [8][4096][32] bf16  (2 MB)
  u16* ks = qs + (NH * NN * 32);              // [8][4096][32] bf16  (2 MB)
  u16* vT = ks + (NH * MM * 32);              // [8][32][4096] bf16  (2 MB, key-permuted)
  float* accP = (float*)(vT + (NH * MM * 32)); // [S][4096][256] f32 partials
  // key-split by available scratch: S=4 needs 6 + 16 + 0.5 MB
  const int S = (ws_size >= (size_t)(6 + 16) * 1024 * 1024 + 512 * 1024) ? 4 : 1;
  float* lsumP = accP + (size_t)S * (NN * 256); // [S][8][4096] f32

  hipLaunchKernelGGL(proj_kernel, dim3(384), dim3(256), 0, stream,
                     x, y, Wq, bq, Wk, bk, Wv, bv, qs, ks, vT);
  hipLaunchKernelGGL(flash_kernel, dim3(64, NH, S), dim3(256), 0, stream,
                     qs, ks, vT, accP, lsumP);
  hipLaunchKernelGGL(out_gemm_kernel, dim3(256), dim3(256), 0, stream,
                     accP, lsumP, Wo, bo, out, S);
}

// Round 7
// 61.884 us; speedup vs baseline: 1.1841x; 1.1841x over previous
//
#include <hip/hip_runtime.h>
#include <hip/hip_bf16.h>

typedef __attribute__((ext_vector_type(8))) short bf16x8;
typedef __attribute__((ext_vector_type(4))) float f32x4;
typedef unsigned short u16;
typedef unsigned int u32;

#define NH 8
#define NN 4096
#define MM 4096

__device__ __forceinline__ u16 f2bf(float f) {
  u32 b = __float_as_uint(f);
  b += 0x7FFFu + ((b >> 16) & 1u);   // RNE to bf16
  return (u16)(b >> 16);
}

// pack two positive floats to bf16 pair {lo:a, hi:b}, round-half-up
__device__ __forceinline__ u32 pack_rnu(float a, float b) {
  u32 ua = __float_as_uint(a) + 0x8000u;
  u32 ub = __float_as_uint(b) + 0x8000u;
#if __has_builtin(__builtin_amdgcn_perm)
  return __builtin_amdgcn_perm(ub, ua, 0x07060302u);  // {ua.b2,ua.b3,ub.b2,ub.b3}
#else
  return (ua >> 16) | (ub & 0xFFFF0000u);
#endif
}

#if __has_builtin(__builtin_amdgcn_exp2f)
__device__ __forceinline__ float exp2_fast(float x) { return __builtin_amdgcn_exp2f(x); }
#else
__device__ __forceinline__ float exp2_fast(float x) { return __expf(x * 0.69314718055994531f); }
#endif

// ---------------- fused projections: blocks 0..255 = q/k, 256..383 = v ----------------
// v is written transposed AND key-permuted within each 32-key chunk:
//   position p (0..31) holds key k(p) = 16*((p>>2)&1) + 4*(p>>3) + (p&3)
// so flash's PV A-fragment (slot map k = 4g+(j&3)+16(j>>2)) is one b128 at 8g.
__global__ __launch_bounds__(256) void proj_kernel(
    const float* __restrict__ x, const float* __restrict__ y,
    const float* __restrict__ Wq, const float* __restrict__ bq,
    const float* __restrict__ Wk, const float* __restrict__ bk,
    const float* __restrict__ Wv, const float* __restrict__ bv,
    u16* __restrict__ qs, u16* __restrict__ ks, u16* __restrict__ vT)
{
  __shared__ u16 sv[256][33];
  const int bid = blockIdx.x;
  const int tid = threadIdx.x;
  if (bid < 256) {
    // ---- q/k path ----
    int idx = bid * 256 + tid;                  // 65536 total
    int t = idx >> 15;                          // 0 = q (from x), 1 = k (from y)
    int h = (idx >> 12) & 7;
    int row = idx & 4095;
    const float* src = (t ? y : x) + row * 16;
    const float* W = (t ? Wk : Wq) + (h << 9);
    const float* b = (t ? bk : bq) + (h << 5);
    // q scale = (1/sqrt(32)) * log2(e) so softmax is exp2(score)
    const float scale = t ? 1.0f : 0.25503635116465163f;
    float4 r4[4];
#pragma unroll
    for (int i = 0; i < 4; ++i) r4[i] = ((const float4*)src)[i];
    const float* r = (const float*)r4;
    u16* out = (t ? ks : qs) + (idx & 32767) * 32;      // (h*4096+row)*32
#pragma unroll
    for (int j = 0; j < 32; ++j) {
      float a = b[j];
#pragma unroll
      for (int i = 0; i < 16; ++i) a = fmaf(r[i], W[i * 32 + j], a);
      out[j] = f2bf(a * scale);
    }
  } else {
    // ---- v path ----
    int vb = bid - 256;
    int h = vb >> 4;
    int kb = (vb & 15) << 8;           // 256 keys per block
    const float* src = y + (kb + tid) * 16;
    const float* W = Wv + (h << 9);
    const float* b = bv + (h << 5);
    float4 r4[4];
#pragma unroll
    for (int i = 0; i < 4; ++i) r4[i] = ((const float4*)src)[i];
    const float* r = (const float*)r4;
#pragma unroll
    for (int j = 0; j < 32; ++j) {
      float a = b[j];
#pragma unroll
      for (int i = 0; i < 16; ++i) a = fmaf(r[i], W[i * 32 + j], a);
      sv[tid][j] = f2bf(a);
    }
    __syncthreads();
    int dv = tid >> 3;
    int c = (tid & 7) << 5;            // 32-key chunk
    u16* dst = vT + (((h << 5) + dv) << 12) + kb + c;
#pragma unroll
    for (int q = 0; q < 4; ++q) {      // positions 8q..8q+7 <- keys {4q+r, 16+4q+r}
      uint4 w;
      w.x = (u32)sv[c + 4 * q + 0][dv]      | ((u32)sv[c + 4 * q + 1][dv] << 16);
      w.y = (u32)sv[c + 4 * q + 2][dv]      | ((u32)sv[c + 4 * q + 3][dv] << 16);
      w.z = (u32)sv[c + 16 + 4 * q + 0][dv] | ((u32)sv[c + 16 + 4 * q + 1][dv] << 16);
      w.w = (u32)sv[c + 16 + 4 * q + 2][dv] | ((u32)sv[c + 16 + 4 * q + 3][dv] << 16);
      *(uint4*)(dst + q * 8) = w;
    }
  }
}

// ---------------- flash attention (key-split partials): S^T = K Q^T, O^T = V^T P^T ----
// Round-4/5 verified inner structure; NEW: each wave owns 32 q-rows (two Q
// fragments) so each K/V b128 LDS read serves 2x the MFMA/softmax work.
// Block covers 128 q-rows; grid (NN/128, NH, S).
#define KST 40                  // K LDS row stride in u16 (80 B, 16B-aligned)
#define VST 72                  // V LDS row stride in u16 (144 B, 16B-aligned)
#define VSZ (32 * VST)          // one 64-key V sub-tile

__global__ __launch_bounds__(256) void flash_kernel(
    const u16* __restrict__ qs, const u16* __restrict__ ksrc,
    const u16* __restrict__ vT, float* __restrict__ accP,
    float* __restrict__ lsumP)
{
  __shared__ u16 sK[128 * KST];    // 128 keys x 32 dq  (10240 B)
  __shared__ u16 sVT[2 * VSZ];     // 2 sub x 32 dv x 64 keys (9216 B)
  const int h = blockIdx.y;
  const int qt = blockIdx.x;
  const int z = blockIdx.z;
  const int nIter = (MM / 128) / gridDim.z;        // stages of 128 keys
  const int kb0 = z * (MM / gridDim.z);            // first key of this split
  const int tid = threadIdx.x;
  const int wv = tid >> 6;
  const int lane = tid & 63;
  const int d = lane & 15;        // qrow-in-16 / A-row index / C col
  const int g = lane >> 4;        // lane group
  const int qrowA = (qt << 7) + (wv << 5) + d;     // wave owns rows [wv*32, wv*32+32)
  const int qrowB = qrowA + 16;

  union U4 { uint4 q; bf16x8 v; };
  // Q fragments, contiguous k-relabel: slot (g,j) -> k = 8g+j (same map on K side)
  U4 qfA, qfB;
  qfA.q = *(const uint4*)(qs + (((h << 12) + qrowA) << 5) + (g << 3));
  qfB.q = *(const uint4*)(qs + (((h << 12) + qrowB) << 5) + (g << 3));

  float lsA = 0.f, lsB = 0.f;
  f32x4 accA0 = {0.f, 0.f, 0.f, 0.f}, accA1 = {0.f, 0.f, 0.f, 0.f};
  f32x4 accB0 = {0.f, 0.f, 0.f, 0.f}, accB1 = {0.f, 0.f, 0.f, 0.f};
  const f32x4 zero = {0.f, 0.f, 0.f, 0.f};

  // staging addresses
  const u16* gK = ksrc + (h << 17) + (kb0 << 5) + ((tid >> 1) << 5) + ((tid & 1) << 4);
  const u16* gV = vT + (((h << 5) + (tid >> 3)) << 12) + kb0 + ((tid & 7) << 4);
  u16* wK = sK + (tid >> 1) * KST + ((tid & 1) << 4);
  u16* wV = sVT + ((tid & 7) >> 2) * VSZ + (tid >> 3) * VST + ((tid & 7) & 3) * 16;

  // prologue: stage this split's first 128 keys
  {
    uint4 a = *(const uint4*)gK, b = *(const uint4*)(gK + 8);
    uint4 c = *(const uint4*)gV, e = *(const uint4*)(gV + 8);
    *(uint4*)wK = a; *(uint4*)(wK + 8) = b;
    *(uint4*)wV = c; *(uint4*)(wV + 8) = e;
  }
  __syncthreads();

  auto compute = [&](const u16* kb, const u16* vb) {
    U4 kf[4];
#pragma unroll
    for (int t = 0; t < 4; ++t)     // K frags: keys 16t+d, k = 8g+j contiguous
      kf[t].q = *(const uint4*)(kb + (t * 16 + d) * KST + (g << 3));

    union { u32 w[4]; bf16x8 v; } pbA0, pbA1, pbB0, pbB1;
    {
      f32x4 s0, s1, s2, s3;
      s0 = __builtin_amdgcn_mfma_f32_16x16x32_bf16(kf[0].v, qfA.v, zero, 0, 0, 0);
      s1 = __builtin_amdgcn_mfma_f32_16x16x32_bf16(kf[1].v, qfA.v, zero, 0, 0, 0);
      s2 = __builtin_amdgcn_mfma_f32_16x16x32_bf16(kf[2].v, qfA.v, zero, 0, 0, 0);
      s3 = __builtin_amdgcn_mfma_f32_16x16x32_bf16(kf[3].v, qfA.v, zero, 0, 0, 0);
      float e[16];
      e[0]=exp2_fast(s0.x); e[1]=exp2_fast(s0.y); e[2]=exp2_fast(s0.z); e[3]=exp2_fast(s0.w);
      e[4]=exp2_fast(s1.x); e[5]=exp2_fast(s1.y); e[6]=exp2_fast(s1.z); e[7]=exp2_fast(s1.w);
      e[8]=exp2_fast(s2.x); e[9]=exp2_fast(s2.y); e[10]=exp2_fast(s2.z); e[11]=exp2_fast(s2.w);
      e[12]=exp2_fast(s3.x); e[13]=exp2_fast(s3.y); e[14]=exp2_fast(s3.z); e[15]=exp2_fast(s3.w);
      lsA += ((e[0]+e[1])+(e[2]+e[3])) + ((e[4]+e[5])+(e[6]+e[7]))
           + ((e[8]+e[9])+(e[10]+e[11])) + ((e[12]+e[13])+(e[14]+e[15]));
      pbA0.w[0] = pack_rnu(e[0], e[1]);   pbA0.w[1] = pack_rnu(e[2], e[3]);
      pbA0.w[2] = pack_rnu(e[4], e[5]);   pbA0.w[3] = pack_rnu(e[6], e[7]);
      pbA1.w[0] = pack_rnu(e[8], e[9]);   pbA1.w[1] = pack_rnu(e[10], e[11]);
      pbA1.w[2] = pack_rnu(e[12], e[13]); pbA1.w[3] = pack_rnu(e[14], e[15]);
    }
    {
      f32x4 s0, s1, s2, s3;
      s0 = __builtin_amdgcn_mfma_f32_16x16x32_bf16(kf[0].v, qfB.v, zero, 0, 0, 0);
      s1 = __builtin_amdgcn_mfma_f32_16x16x32_bf16(kf[1].v, qfB.v, zero, 0, 0, 0);
      s2 = __builtin_amdgcn_mfma_f32_16x16x32_bf16(kf[2].v, qfB.v, zero, 0, 0, 0);
      s3 = __builtin_amdgcn_mfma_f32_16x16x32_bf16(kf[3].v, qfB.v, zero, 0, 0, 0);
      float e[16];
      e[0]=exp2_fast(s0.x); e[1]=exp2_fast(s0.y); e[2]=exp2_fast(s0.z); e[3]=exp2_fast(s0.w);
      e[4]=exp2_fast(s1.x); e[5]=exp2_fast(s1.y); e[6]=exp2_fast(s1.z); e[7]=exp2_fast(s1.w);
      e[8]=exp2_fast(s2.x); e[9]=exp2_fast(s2.y); e[10]=exp2_fast(s2.z); e[11]=exp2_fast(s2.w);
      e[12]=exp2_fast(s3.x); e[13]=exp2_fast(s3.y); e[14]=exp2_fast(s3.z); e[15]=exp2_fast(s3.w);
      lsB += ((e[0]+e[1])+(e[2]+e[3])) + ((e[4]+e[5])+(e[6]+e[7]))
           + ((e[8]+e[9])+(e[10]+e[11])) + ((e[12]+e[13])+(e[14]+e[15]));
      pbB0.w[0] = pack_rnu(e[0], e[1]);   pbB0.w[1] = pack_rnu(e[2], e[3]);
      pbB0.w[2] = pack_rnu(e[4], e[5]);   pbB0.w[3] = pack_rnu(e[6], e[7]);
      pbB1.w[0] = pack_rnu(e[8], e[9]);   pbB1.w[1] = pack_rnu(e[10], e[11]);
      pbB1.w[2] = pack_rnu(e[12], e[13]); pbB1.w[3] = pack_rnu(e[14], e[15]);
    }
    // V frags (vT key-permuted: group-g slot block at position 8g), serve both halves
    U4 vf0, vf1, vf2, vf3;
    const u16* vp = vb + d * VST;
    vf0.q = *(const uint4*)(vp + (g << 3));
    vf1.q = *(const uint4*)(vp + 32 + (g << 3));
    vp += 16 * VST;
    vf2.q = *(const uint4*)(vp + (g << 3));
    vf3.q = *(const uint4*)(vp + 32 + (g << 3));
    accA0 = __builtin_amdgcn_mfma_f32_16x16x32_bf16(vf0.v, pbA0.v, accA0, 0, 0, 0);
    accA0 = __builtin_amdgcn_mfma_f32_16x16x32_bf16(vf1.v, pbA1.v, accA0, 0, 0, 0);
    accA1 = __builtin_amdgcn_mfma_f32_16x16x32_bf16(vf2.v, pbA0.v, accA1, 0, 0, 0);
    accA1 = __builtin_amdgcn_mfma_f32_16x16x32_bf16(vf3.v, pbA1.v, accA1, 0, 0, 0);
    accB0 = __builtin_amdgcn_mfma_f32_16x16x32_bf16(vf0.v, pbB0.v, accB0, 0, 0, 0);
    accB0 = __builtin_amdgcn_mfma_f32_16x16x32_bf16(vf1.v, pbB1.v, accB0, 0, 0, 0);
    accB1 = __builtin_amdgcn_mfma_f32_16x16x32_bf16(vf2.v, pbB0.v, accB1, 0, 0, 0);
    accB1 = __builtin_amdgcn_mfma_f32_16x16x32_bf16(vf3.v, pbB1.v, accB1, 0, 0, 0);
  };

#pragma unroll 1
  for (int it = 0; it < nIter; ++it) {
    uint4 a, b, c, e;
    if (it < nIter - 1) {            // prefetch next 128 keys into registers
      gK += 4096; gV += 128;
      a = *(const uint4*)gK; b = *(const uint4*)(gK + 8);
      c = *(const uint4*)gV; e = *(const uint4*)(gV + 8);
    }
    compute(sK, sVT);
    compute(sK + 64 * KST, sVT + VSZ);
    __syncthreads();               // all reads of current stage done
    if (it < nIter - 1) {
      *(uint4*)wK = a; *(uint4*)(wK + 8) = b;   // vmcnt drained under compute
      *(uint4*)wV = c; *(uint4*)(wV + 8) = e;
      __syncthreads();             // stage visible
    }
  }

  // cross-lane reduce of this split's denominators; store per qrow (g==0 lanes)
  lsA += __shfl_xor(lsA, 16);
  lsA += __shfl_xor(lsA, 32);
  lsB += __shfl_xor(lsB, 16);
  lsB += __shfl_xor(lsB, 32);
  if (g == 0) {
    lsumP[((z * NH + h) << 12) + qrowA] = lsA;
    lsumP[((z * NH + h) << 12) + qrowB] = lsB;
  }
  // unnormalized partial O
  float* cpA = accP + z * (NN * 256) + (qrowA << 8) + (h << 5) + (g << 2);
  *(float4*)cpA        = make_float4(accA0.x, accA0.y, accA0.z, accA0.w);
  *(float4*)(cpA + 16) = make_float4(accA1.x, accA1.y, accA1.z, accA1.w);
  float* cpB = accP + z * (NN * 256) + (qrowB << 8) + (h << 5) + (g << 2);
  *(float4*)cpB        = make_float4(accB0.x, accB0.y, accB0.z, accB0.w);
  *(float4*)(cpB + 16) = make_float4(accB1.x, accB1.y, accB1.z, accB1.w);
}

// ---------------- combine: concat = (sum_s accP) / (sum_s lsum) ----------------
__global__ __launch_bounds__(256) void combine_kernel(
    const float* __restrict__ accP, const float* __restrict__ lsumP,
    float* __restrict__ concat, int S)
{
  int idx = blockIdx.x * 256 + threadIdx.x;  // over 4096*256
  int n = idx >> 8;
  int h = (idx & 255) >> 5;
  float o = 0.f, l = 0.f;
  for (int s = 0; s < S; ++s) {
    o += accP[s * (NN * 256) + idx];
    l += lsumP[((s * NH + h) << 12) + n];
  }
  concat[idx] = o / l;
}

// ---------------- output projection: out = concat @ Wo + bo ----------------
__global__ __launch_bounds__(256) void out_gemm_kernel(
    const float* __restrict__ concat, const float* __restrict__ Wo,
    const float* __restrict__ bo, float* __restrict__ out)
{
  __shared__ float sWo[4096];
  int tid = threadIdx.x;
  for (int i = tid; i < 4096; i += 256) sWo[i] = Wo[i];
  __syncthreads();
  int idx = blockIdx.x * 256 + tid;
  int n = idx >> 4;
  int c = idx & 15;
  const float4* crow = (const float4*)(concat + (n << 8));
  float a = bo[c];
#pragma unroll 4
  for (int i4 = 0; i4 < 64; ++i4) {
    float4 cv = crow[i4];
    a = fmaf(cv.x, sWo[(i4 * 4 + 0) * 16 + c], a);
    a = fmaf(cv.y, sWo[(i4 * 4 + 1) * 16 + c], a);
    a = fmaf(cv.z, sWo[(i4 * 4 + 2) * 16 + c], a);
    a = fmaf(cv.w, sWo[(i4 * 4 + 3) * 16 + c], a);
  }
  out[idx] = a;
}

extern "C" void kernel_launch(void* const* d_in, const int* in_sizes, int n_in,
                              void* d_out, int out_size, void* d_ws, size_t ws_size,
                              hipStream_t stream) {
  const float* x  = (const float*)d_in[0];
  const float* y  = (const float*)d_in[1];
  const float* Wq = (const float*)d_in[2];
  const float* bq = (const float*)d_in[3];
  const float* Wk = (const float*)d_in[4];
  const float* bk = (const float*)d_in[5];
  const float* Wv = (const float*)d_in[6];
  const float* bv = (const float*)d_in[7];
  const float* Wo = (const float*)d_in[8];
  const float* bo = (const float*)d_in[9];
  float* out = (float*)d_out;

  u16* qs = (u16*)d_ws;                       // [8][4096][32] bf16  (2 MB)
  u16* ks = qs + (NH * NN * 32);              // [8][4096][32] bf16  (2 MB)
  u16* vT = ks + (NH * MM * 32);              // [8][32][4096] bf16  (2 MB, key-permuted)
  float* concat = (float*)(vT + (NH * MM * 32)); // [4096][256] f32
  float* accP = concat;                       // partial O: S regions of 4 MB (accP[0]==concat)
  // key-split by available scratch: S=4 needs 6 + 16 + 0.5 MB
  const int S = (ws_size >= (size_t)(6 + 16) * 1024 * 1024 + 512 * 1024) ? 4 : 1;
  float* lsumP = accP + (size_t)S * (NN * 256); // [S][8][4096] f32

  hipLaunchKernelGGL(proj_kernel, dim3(384), dim3(256), 0, stream,
                     x, y, Wq, bq, Wk, bk, Wv, bv, qs, ks, vT);
  hipLaunchKernelGGL(flash_kernel, dim3(32, NH, S), dim3(256), 0, stream,
                     qs, ks, vT, accP, lsumP);
  hipLaunchKernelGGL(combine_kernel, dim3(4096), dim3(256), 0, stream,
                     accP, lsumP, concat, S);
  hipLaunchKernelGGL(out_gemm_kernel, dim3(256), dim3(256), 0, stream, concat, Wo, bo, out);
}